// Round 8
// baseline (172.161 us; speedup 1.0000x reference)
//
#include <hip/hip_runtime.h>

// Problem constants
#define BB 32
#define CC 1024
#define QQ 64
#define EE 256
#define FE 1024
#define MM (BB*CC)   // 32768

typedef __bf16 bf16_t;
typedef bf16_t bf16x8 __attribute__((ext_vector_type(8)));
typedef float f32x4 __attribute__((ext_vector_type(4)));
typedef unsigned short u16x8 __attribute__((ext_vector_type(8)));

__device__ __forceinline__ unsigned short f2bf(float f) {
  unsigned u = __float_as_uint(f);
  u += 0x7fffu + ((u >> 16) & 1u);   // RNE
  return (unsigned short)(u >> 16);
}
__device__ __forceinline__ float bf2f(unsigned short u) {
  return __uint_as_float(((unsigned)u) << 16);
}

__device__ __forceinline__ void gload_lds16(const void* g, void* l) {
  __builtin_amdgcn_global_load_lds(
      (const __attribute__((address_space(1))) unsigned int*)g,
      (__attribute__((address_space(3))) unsigned int*)l, 16, 0, 0);
}

// ---------------------------------------------------------------- prep: qw = question.w_question; cast W to bf16
__global__ void k_prep(const float* __restrict__ question, const float* __restrict__ w_question,
                       float* __restrict__ qw,
                       const float* __restrict__ W, unsigned short* __restrict__ Wb) {
  int bx = blockIdx.x;
  if (bx < 512) {
    int gid = bx * 256 + threadIdx.x;
    int row = gid >> 6;            // (b*QQ + q), 0..2047
    int lane = gid & 63;
    const float4 q = *(const float4*)(question + (size_t)row * EE + lane * 4);
    const float4 wq = *(const float4*)(w_question + lane * 4);
    float d = q.x*wq.x + q.y*wq.y + q.z*wq.z + q.w*wq.w;
    d += __shfl_xor(d, 1);  d += __shfl_xor(d, 2);  d += __shfl_xor(d, 4);
    d += __shfl_xor(d, 8);  d += __shfl_xor(d, 16); d += __shfl_xor(d, 32);
    if (lane == 0) qw[row] = d;
  } else {
    int i = ((bx - 512) * 256 + threadIdx.x) * 4;
    float4 v = *(const float4*)(W + i);
    ushort4 o; o.x = f2bf(v.x); o.y = f2bf(v.y); o.z = f2bf(v.z); o.w = f2bf(v.w);
    *(ushort4*)(Wb + i) = o;
  }
}

#define DOT4(acc, A, Bv) acc += A.x*Bv.x + A.y*Bv.y + A.z*Bv.z + A.w*Bv.w

// ---------------------------------------------------------------- fused similarity + softmax + PV
__launch_bounds__(256)
__global__ void k_simpv(const float* __restrict__ ctx, const float* __restrict__ question,
                        const float* __restrict__ qw_g, const float* __restrict__ w_context,
                        const float* __restrict__ w_multiple,
                        float* __restrict__ rowmax, unsigned short* __restrict__ att) {
  __shared__ float qbuf[QQ * 132];          // sim: [q][128+4]; PV: [q][64+4]
  __shared__ float ck[64][36];              // ctx*w_mult chunk
  __shared__ unsigned short Pl[QQ][68];     // P[q][c] bf16
  __shared__ float cwl[64];
  __shared__ float qwl[QQ];
  const int tid = threadIdx.x;
  const int b = blockIdx.y;
  const int c0 = blockIdx.x * 64;
  const int tx = tid & 15, ty = tid >> 4;

  const float* qb = question + (size_t)b * (QQ * EE);
  if (tid < QQ) qwl[tid] = qw_g[b * QQ + tid];

  const int cr = tid >> 3, er = (tid & 7) * 4;
  const float* crow0 = ctx + ((size_t)(b * CC + c0 + cr)) * EE;
  const float* crow1 = crow0 + 32 * EE;
  unsigned short* arow0 = att + ((size_t)(b * CC + c0 + cr)) * FE;
  unsigned short* arow1 = arow0 + (size_t)32 * FE;
  float s[4][4] = {{0.f}};
  float cp0 = 0.f, cp1 = 0.f;

  for (int h = 0; h < 2; ++h) {
    if (h) __syncthreads();
    for (int idx = tid * 4; idx < QQ * 128; idx += 1024) {
      int row = idx >> 7, col = idx & 127;
      *(float4*)&qbuf[row * 132 + col] = *(const float4*)(qb + (size_t)row * EE + h * 128 + col);
    }
    for (int eo2 = 0; eo2 < 128; eo2 += 32) {
      const int eo = h * 128 + eo2;
      float4 cv0 = *(const float4*)(crow0 + eo + er);
      float4 cv1 = *(const float4*)(crow1 + eo + er);
      float4 wc = *(const float4*)(w_context + eo + er);
      float4 wm = *(const float4*)(w_multiple + eo + er);
      cp0 += cv0.x*wc.x + cv0.y*wc.y + cv0.z*wc.z + cv0.w*wc.w;
      cp1 += cv1.x*wc.x + cv1.y*wc.y + cv1.z*wc.z + cv1.w*wc.w;
      ushort4 u0, u1;
      u0.x = f2bf(cv0.x); u0.y = f2bf(cv0.y); u0.z = f2bf(cv0.z); u0.w = f2bf(cv0.w);
      u1.x = f2bf(cv1.x); u1.y = f2bf(cv1.y); u1.z = f2bf(cv1.z); u1.w = f2bf(cv1.w);
      *(ushort4*)(arow0 + eo + er) = u0;
      *(ushort4*)(arow1 + eo + er) = u1;
      __syncthreads();
      float4 m0, m1;
      m0.x = cv0.x*wm.x; m0.y = cv0.y*wm.y; m0.z = cv0.z*wm.z; m0.w = cv0.w*wm.w;
      m1.x = cv1.x*wm.x; m1.y = cv1.y*wm.y; m1.z = cv1.z*wm.z; m1.w = cv1.w*wm.w;
      *(float4*)&ck[cr][er] = m0;
      *(float4*)&ck[cr + 32][er] = m1;
      __syncthreads();
#pragma unroll
      for (int ee = 0; ee < 32; ee += 4) {
        float4 a0 = *(const float4*)&ck[ty +  0][ee];
        float4 a1 = *(const float4*)&ck[ty + 16][ee];
        float4 a2 = *(const float4*)&ck[ty + 32][ee];
        float4 a3 = *(const float4*)&ck[ty + 48][ee];
        float4 b0 = *(const float4*)&qbuf[(tx +  0) * 132 + eo2 + ee];
        float4 b1 = *(const float4*)&qbuf[(tx + 16) * 132 + eo2 + ee];
        float4 b2 = *(const float4*)&qbuf[(tx + 32) * 132 + eo2 + ee];
        float4 b3 = *(const float4*)&qbuf[(tx + 48) * 132 + eo2 + ee];
        DOT4(s[0][0], a0, b0); DOT4(s[0][1], a0, b1); DOT4(s[0][2], a0, b2); DOT4(s[0][3], a0, b3);
        DOT4(s[1][0], a1, b0); DOT4(s[1][1], a1, b1); DOT4(s[1][2], a1, b2); DOT4(s[1][3], a1, b3);
        DOT4(s[2][0], a2, b0); DOT4(s[2][1], a2, b1); DOT4(s[2][2], a2, b2); DOT4(s[2][3], a2, b3);
        DOT4(s[3][0], a3, b0); DOT4(s[3][1], a3, b1); DOT4(s[3][2], a3, b2); DOT4(s[3][3], a3, b3);
      }
    }
  }
  cp0 += __shfl_xor(cp0, 1); cp0 += __shfl_xor(cp0, 2); cp0 += __shfl_xor(cp0, 4);
  cp1 += __shfl_xor(cp1, 1); cp1 += __shfl_xor(cp1, 2); cp1 += __shfl_xor(cp1, 4);
  if ((tid & 7) == 0) { cwl[cr] = cp0; cwl[cr + 32] = cp1; }
  __syncthreads();

#pragma unroll
  for (int i = 0; i < 4; ++i) {
    int c = ty + 16 * i;
    float cw = cwl[c];
    float f[4], mx = -1e30f;
#pragma unroll
    for (int j = 0; j < 4; ++j) {
      f[j] = s[i][j] + cw + qwl[tx + 16 * j];
      mx = fmaxf(mx, f[j]);
    }
    mx = fmaxf(mx, __shfl_xor(mx, 1));
    mx = fmaxf(mx, __shfl_xor(mx, 2));
    mx = fmaxf(mx, __shfl_xor(mx, 4));
    mx = fmaxf(mx, __shfl_xor(mx, 8));
    float sum = 0.f;
#pragma unroll
    for (int j = 0; j < 4; ++j) { f[j] = expf(f[j] - mx); sum += f[j]; }
    sum += __shfl_xor(sum, 1);
    sum += __shfl_xor(sum, 2);
    sum += __shfl_xor(sum, 4);
    sum += __shfl_xor(sum, 8);
    float inv = 1.f / sum;
    if (tx == 0) rowmax[(size_t)b * CC + c0 + c] = mx;
#pragma unroll
    for (int j = 0; j < 4; ++j) Pl[tx + 16 * j][c] = f2bf(f[j] * inv);
  }
  __syncthreads();

  for (int ep = 0; ep < EE; ep += 64) {
    if (ep) __syncthreads();
    {
      int q = tid >> 2, e16 = (tid & 3) * 16;
      const float* src = qb + (size_t)q * EE + ep + e16;
      *(float4*)&qbuf[q * 68 + e16 +  0] = *(const float4*)(src);
      *(float4*)&qbuf[q * 68 + e16 +  4] = *(const float4*)(src + 4);
      *(float4*)&qbuf[q * 68 + e16 +  8] = *(const float4*)(src + 8);
      *(float4*)&qbuf[q * 68 + e16 + 12] = *(const float4*)(src + 12);
    }
    __syncthreads();
    float s2[4][4] = {{0.f}};
#pragma unroll 8
    for (int q = 0; q < QQ; ++q) {
      float a0 = bf2f(Pl[q][ty +  0]);
      float a1 = bf2f(Pl[q][ty + 16]);
      float a2 = bf2f(Pl[q][ty + 32]);
      float a3 = bf2f(Pl[q][ty + 48]);
      float4 bv = *(const float4*)&qbuf[q * 68 + tx * 4];
      s2[0][0] += a0 * bv.x; s2[0][1] += a0 * bv.y; s2[0][2] += a0 * bv.z; s2[0][3] += a0 * bv.w;
      s2[1][0] += a1 * bv.x; s2[1][1] += a1 * bv.y; s2[1][2] += a1 * bv.z; s2[1][3] += a1 * bv.w;
      s2[2][0] += a2 * bv.x; s2[2][1] += a2 * bv.y; s2[2][2] += a2 * bv.z; s2[2][3] += a2 * bv.w;
      s2[3][0] += a3 * bv.x; s2[3][1] += a3 * bv.y; s2[3][2] += a3 * bv.z; s2[3][3] += a3 * bv.w;
    }
#pragma unroll
    for (int i = 0; i < 4; ++i) {
      int c = ty + 16 * i;
      size_t row = (size_t)(b * CC + c0 + c);
      unsigned short* arow = att + row * (size_t)FE;
      ushort4 cu = *(const ushort4*)(arow + ep + tx * 4);
      float cx = bf2f(cu.x), cy = bf2f(cu.y), cz = bf2f(cu.z), cw = bf2f(cu.w);
      ushort4 o1, o2;
      o1.x = f2bf(s2[i][0]);       o1.y = f2bf(s2[i][1]);       o1.z = f2bf(s2[i][2]);       o1.w = f2bf(s2[i][3]);
      o2.x = f2bf(cx * s2[i][0]);  o2.y = f2bf(cy * s2[i][1]);  o2.z = f2bf(cz * s2[i][2]);  o2.w = f2bf(cw * s2[i][3]);
      *(ushort4*)(arow + 1 * EE + ep + tx * 4) = o1;
      *(ushort4*)(arow + 2 * EE + ep + tx * 4) = o2;
    }
  }
}

// ---------------------------------------------------------------- q2c: softmax over c of rowmax
__global__ void k_q2c_softmax(const float* __restrict__ rowmax, float* __restrict__ q2cw) {
  int b = blockIdx.x, tid = threadIdx.x;
  __shared__ float rbuf[4], sbuf[4];
  float4 v = *(const float4*)(rowmax + (size_t)b * CC + tid * 4);
  float m = fmaxf(fmaxf(v.x, v.y), fmaxf(v.z, v.w));
  for (int off = 1; off < 64; off <<= 1) m = fmaxf(m, __shfl_xor(m, off));
  int wv = tid >> 6;
  if ((tid & 63) == 0) rbuf[wv] = m;
  __syncthreads();
  m = fmaxf(fmaxf(rbuf[0], rbuf[1]), fmaxf(rbuf[2], rbuf[3]));
  float e0 = expf(v.x - m), e1 = expf(v.y - m), e2 = expf(v.z - m), e3 = expf(v.w - m);
  float sum = e0 + e1 + e2 + e3;
  for (int off = 1; off < 64; off <<= 1) sum += __shfl_xor(sum, off);
  if ((tid & 63) == 0) sbuf[wv] = sum;
  __syncthreads();
  sum = sbuf[0] + sbuf[1] + sbuf[2] + sbuf[3];
  float inv = 1.f / sum;
  float4 o; o.x = e0 * inv; o.y = e1 * inv; o.z = e2 * inv; o.w = e3 * inv;
  *(float4*)(q2cw + (size_t)b * CC + tid * 4) = o;
}

// ---------------------------------------------------------------- q2c_att partials: sum_c w[c]*ctx_bf16[b,c,e]
__global__ void k_q2c_part(const unsigned short* __restrict__ att, const float* __restrict__ w,
                           float* __restrict__ part) {
  int b = blockIdx.y, ch = blockIdx.x;
  int e = threadIdx.x;
  const unsigned short* base = att + ((size_t)(b * CC + ch * 128)) * FE + e;
  const float* wp = w + b * CC + ch * 128;
  float acc = 0.f;
#pragma unroll 4
  for (int c = 0; c < 128; ++c) acc += wp[c] * bf2f(base[(size_t)c * FE]);
  part[(b * 8 + ch) * EE + e] = acc;
}

__global__ void k_q2c_sum(const float* __restrict__ part, float* __restrict__ q2catt) {
  int b = blockIdx.x, e = threadIdx.x;
  float a = 0.f;
#pragma unroll
  for (int ch = 0; ch < 8; ++ch) a += part[(b * 8 + ch) * EE + e];
  q2catt[b * EE + e] = a;
}

// ---------------------------------------------------------------- att3 = bf16(ctx_bf16 * q2catt)
__global__ void k_att3(const unsigned short* __restrict__ att_ro, const float* __restrict__ q2catt,
                       unsigned short* __restrict__ att_wr) {
  int unit = blockIdx.x * 256 + threadIdx.x;     // 32768 rows * 32 chunks
  int row = unit >> 5;
  int e8 = (unit & 31) * 8;
  int b = row >> 10;
  u16x8 c = *(const u16x8*)(att_ro + (size_t)row * FE + e8);
  float4 g0 = *(const float4*)(q2catt + b * EE + e8);
  float4 g1 = *(const float4*)(q2catt + b * EE + e8 + 4);
  u16x8 o;
  o[0] = f2bf(bf2f(c[0]) * g0.x); o[1] = f2bf(bf2f(c[1]) * g0.y);
  o[2] = f2bf(bf2f(c[2]) * g0.z); o[3] = f2bf(bf2f(c[3]) * g0.w);
  o[4] = f2bf(bf2f(c[4]) * g1.x); o[5] = f2bf(bf2f(c[5]) * g1.y);
  o[6] = f2bf(bf2f(c[6]) * g1.z); o[7] = f2bf(bf2f(c[7]) * g1.w);
  *(u16x8*)(att_wr + (size_t)row * FE + 3 * EE + e8) = o;
}

// ---------------------------------------------------------------- final GEMM: out = attended @ W^T + b, masked
// m97 configuration: 128x128 tile, BK=32, SINGLE-buffered 16 KB LDS, 4 waves,
// plain 2-barrier loop, 3 blocks/CU co-resident (TLP hides barrier drains).
// XOR-swizzled LDS (granule ^= row&3, via pre-swizzled global source), XCD-chunked grid.
__launch_bounds__(256, 3)
__global__ void k_gemm(const unsigned short* __restrict__ A, const unsigned short* __restrict__ Bw,
                       const float* __restrict__ bias, const float* __restrict__ mask,
                       float* __restrict__ out) {
  __shared__ bf16_t As[128][32];
  __shared__ bf16_t Bs[128][32];
  const int tid = threadIdx.x;
  const int lane = tid & 63;
  const int wave = tid >> 6;
  const int wr = wave >> 1, wc = wave & 1;

  // XCD-chunked swizzle: 2048 blocks, 8 XCDs -> 256 contiguous wgs per XCD
  // (32 row-panels x 8 col-tiles, col fastest -> A-panel L2-resident per XCD).
  const int bid = blockIdx.x;
  const int wg = (bid & 7) * 256 + (bid >> 3);
  const int bcol = (wg & 7) * 128;
  const int brow = (wg >> 3) * 128;

  const int r = lane & 15, kg = lane >> 4;
  const int rk = (kg ^ (r & 3)) * 8;        // swizzled k-granule byte offset for frag reads

  // staging: one 16B granule per thread per instr; dest linear in tid (gload_lds requirement).
  const int srow = tid >> 2;                // 0..63
  const int sgr = tid & 3;                  // granule 0..3
  const int ssw = (sgr ^ (srow & 3)) * 8;   // pre-swizzled source granule
  const unsigned short* gA0 = A  + (size_t)(brow + srow) * FE + ssw;
  const unsigned short* gA1 = gA0 + (size_t)64 * FE;     // (srow+64)&3 == srow&3
  const unsigned short* gB0 = Bw + (size_t)(bcol + srow) * FE + ssw;
  const unsigned short* gB1 = gB0 + (size_t)64 * FE;
  bf16_t* dA0 = &As[srow][sgr * 8];
  bf16_t* dA1 = dA0 + 64 * 32;
  bf16_t* dB0 = &Bs[srow][sgr * 8];
  bf16_t* dB1 = dB0 + 64 * 32;

  f32x4 acc[4][4] = {};

  for (int k0 = 0; k0 < FE; k0 += 32) {
    gload_lds16(gA0 + k0, dA0);
    gload_lds16(gA1 + k0, dA1);
    gload_lds16(gB0 + k0, dB0);
    gload_lds16(gB1 + k0, dB1);
    __syncthreads();                       // drains vmcnt: tile ready
    bf16x8 fa[4], fb[4];
#pragma unroll
    for (int m = 0; m < 4; ++m) fa[m] = *(const bf16x8*)&As[wr * 64 + m * 16 + r][rk];
#pragma unroll
    for (int n = 0; n < 4; ++n) fb[n] = *(const bf16x8*)&Bs[wc * 64 + n * 16 + r][rk];
#pragma unroll
    for (int m = 0; m < 4; ++m)
#pragma unroll
      for (int n = 0; n < 4; ++n)
        acc[m][n] = __builtin_amdgcn_mfma_f32_16x16x32_bf16(fa[m], fb[n], acc[m][n], 0, 0, 0);
    __syncthreads();                       // all reads done before next-iter overwrite
  }

#pragma unroll
  for (int m = 0; m < 4; ++m) {
#pragma unroll
    for (int n = 0; n < 4; ++n) {
#pragma unroll
      for (int reg = 0; reg < 4; ++reg) {
        int row = brow + wr * 64 + m * 16 + kg * 4 + reg;
        int col = bcol + wc * 64 + n * 16 + r;
        out[(size_t)row * FE + col] = (acc[m][n][reg] + bias[col]) * mask[row];
      }
    }
  }
}

// ---------------------------------------------------------------- launch
extern "C" void kernel_launch(void* const* d_in, const int* in_sizes, int n_in,
                              void* d_out, int out_size, void* d_ws, size_t ws_size,
                              hipStream_t stream) {
  const float* ctx  = (const float*)d_in[0];
  const float* ques = (const float*)d_in[1];
  const float* mask = (const float*)d_in[2];
  const float* w_q  = (const float*)d_in[3];
  const float* w_c  = (const float*)d_in[4];
  const float* w_m  = (const float*)d_in[5];
  const float* fW   = (const float*)d_in[6];
  const float* fb   = (const float*)d_in[7];
  float* out = (float*)d_out;

  char* ws = (char*)d_ws;
  float* qw     = (float*)(ws);                        //     8,192 B
  float* rowmax = (float*)(ws + 8192);                 //   131,072 B
  float* q2cw   = (float*)(ws + 139264);               //   131,072 B
  float* part   = (float*)(ws + 270336);               //   262,144 B
  float* q2catt = (float*)(ws + 532480);               //    32,768 B
  unsigned short* attended = (unsigned short*)(ws + 1048576);   // 67,108,864 B
  unsigned short* Wb       = (unsigned short*)(ws + 68157440);  //  2,097,152 B

  k_prep<<<1536, 256, 0, stream>>>(ques, w_q, qw, fW, Wb);
  k_simpv<<<dim3(16, 32), 256, 0, stream>>>(ctx, ques, qw, w_c, w_m, rowmax, attended);
  k_q2c_softmax<<<32, 256, 0, stream>>>(rowmax, q2cw);
  k_q2c_part<<<dim3(8, 32), 256, 0, stream>>>(attended, q2cw, part);
  k_q2c_sum<<<32, 256, 0, stream>>>(part, q2catt);
  k_att3<<<4096, 256, 0, stream>>>(attended, q2catt, attended);
  k_gemm<<<2048, 256, 0, stream>>>(attended, Wb, fb, mask, out);
}

// Round 9
// 168.821 us; speedup vs baseline: 1.0198x; 1.0198x over previous
//
#include <hip/hip_runtime.h>

// Problem constants
#define BB 32
#define CC 1024
#define QQ 64
#define EE 256
#define FE 1024
#define MM (BB*CC)   // 32768

typedef __bf16 bf16_t;
typedef bf16_t bf16x8 __attribute__((ext_vector_type(8)));
typedef float f32x4 __attribute__((ext_vector_type(4)));
typedef unsigned short u16x8 __attribute__((ext_vector_type(8)));

__device__ __forceinline__ unsigned short f2bf(float f) {
  unsigned u = __float_as_uint(f);
  u += 0x7fffu + ((u >> 16) & 1u);   // RNE
  return (unsigned short)(u >> 16);
}
__device__ __forceinline__ float bf2f(unsigned short u) {
  return __uint_as_float(((unsigned)u) << 16);
}

__device__ __forceinline__ void gload_lds16(const void* g, void* l) {
  __builtin_amdgcn_global_load_lds(
      (const __attribute__((address_space(1))) unsigned int*)g,
      (__attribute__((address_space(3))) unsigned int*)l, 16, 0, 0);
}

// ---------------------------------------------------------------- prep: qw = question.w_question; cast W to bf16
__global__ void k_prep(const float* __restrict__ question, const float* __restrict__ w_question,
                       float* __restrict__ qw,
                       const float* __restrict__ W, unsigned short* __restrict__ Wb) {
  int bx = blockIdx.x;
  if (bx < 512) {
    int gid = bx * 256 + threadIdx.x;
    int row = gid >> 6;            // (b*QQ + q), 0..2047
    int lane = gid & 63;
    const float4 q = *(const float4*)(question + (size_t)row * EE + lane * 4);
    const float4 wq = *(const float4*)(w_question + lane * 4);
    float d = q.x*wq.x + q.y*wq.y + q.z*wq.z + q.w*wq.w;
    d += __shfl_xor(d, 1);  d += __shfl_xor(d, 2);  d += __shfl_xor(d, 4);
    d += __shfl_xor(d, 8);  d += __shfl_xor(d, 16); d += __shfl_xor(d, 32);
    if (lane == 0) qw[row] = d;
  } else {
    int i = ((bx - 512) * 256 + threadIdx.x) * 4;
    float4 v = *(const float4*)(W + i);
    ushort4 o; o.x = f2bf(v.x); o.y = f2bf(v.y); o.z = f2bf(v.z); o.w = f2bf(v.w);
    *(ushort4*)(Wb + i) = o;
  }
}

#define DOT4(acc, A, Bv) acc += A.x*Bv.x + A.y*Bv.y + A.z*Bv.z + A.w*Bv.w

// ---------------------------------------------------------------- fused similarity + softmax + PV
__launch_bounds__(256)
__global__ void k_simpv(const float* __restrict__ ctx, const float* __restrict__ question,
                        const float* __restrict__ qw_g, const float* __restrict__ w_context,
                        const float* __restrict__ w_multiple,
                        float* __restrict__ rowmax, unsigned short* __restrict__ att) {
  __shared__ float qbuf[QQ * 132];          // sim: [q][128+4]; PV: [q][64+4]
  __shared__ float ck[64][36];              // ctx*w_mult chunk
  __shared__ unsigned short Pl[QQ][68];     // P[q][c] bf16
  __shared__ float cwl[64];
  __shared__ float qwl[QQ];
  const int tid = threadIdx.x;
  const int b = blockIdx.y;
  const int c0 = blockIdx.x * 64;
  const int tx = tid & 15, ty = tid >> 4;

  const float* qb = question + (size_t)b * (QQ * EE);
  if (tid < QQ) qwl[tid] = qw_g[b * QQ + tid];

  const int cr = tid >> 3, er = (tid & 7) * 4;
  const float* crow0 = ctx + ((size_t)(b * CC + c0 + cr)) * EE;
  const float* crow1 = crow0 + 32 * EE;
  unsigned short* arow0 = att + ((size_t)(b * CC + c0 + cr)) * FE;
  unsigned short* arow1 = arow0 + (size_t)32 * FE;
  float s[4][4] = {{0.f}};
  float cp0 = 0.f, cp1 = 0.f;

  for (int h = 0; h < 2; ++h) {
    if (h) __syncthreads();
    for (int idx = tid * 4; idx < QQ * 128; idx += 1024) {
      int row = idx >> 7, col = idx & 127;
      *(float4*)&qbuf[row * 132 + col] = *(const float4*)(qb + (size_t)row * EE + h * 128 + col);
    }
    for (int eo2 = 0; eo2 < 128; eo2 += 32) {
      const int eo = h * 128 + eo2;
      float4 cv0 = *(const float4*)(crow0 + eo + er);
      float4 cv1 = *(const float4*)(crow1 + eo + er);
      float4 wc = *(const float4*)(w_context + eo + er);
      float4 wm = *(const float4*)(w_multiple + eo + er);
      cp0 += cv0.x*wc.x + cv0.y*wc.y + cv0.z*wc.z + cv0.w*wc.w;
      cp1 += cv1.x*wc.x + cv1.y*wc.y + cv1.z*wc.z + cv1.w*wc.w;
      ushort4 u0, u1;
      u0.x = f2bf(cv0.x); u0.y = f2bf(cv0.y); u0.z = f2bf(cv0.z); u0.w = f2bf(cv0.w);
      u1.x = f2bf(cv1.x); u1.y = f2bf(cv1.y); u1.z = f2bf(cv1.z); u1.w = f2bf(cv1.w);
      *(ushort4*)(arow0 + eo + er) = u0;
      *(ushort4*)(arow1 + eo + er) = u1;
      __syncthreads();
      float4 m0, m1;
      m0.x = cv0.x*wm.x; m0.y = cv0.y*wm.y; m0.z = cv0.z*wm.z; m0.w = cv0.w*wm.w;
      m1.x = cv1.x*wm.x; m1.y = cv1.y*wm.y; m1.z = cv1.z*wm.z; m1.w = cv1.w*wm.w;
      *(float4*)&ck[cr][er] = m0;
      *(float4*)&ck[cr + 32][er] = m1;
      __syncthreads();
#pragma unroll
      for (int ee = 0; ee < 32; ee += 4) {
        float4 a0 = *(const float4*)&ck[ty +  0][ee];
        float4 a1 = *(const float4*)&ck[ty + 16][ee];
        float4 a2 = *(const float4*)&ck[ty + 32][ee];
        float4 a3 = *(const float4*)&ck[ty + 48][ee];
        float4 b0 = *(const float4*)&qbuf[(tx +  0) * 132 + eo2 + ee];
        float4 b1 = *(const float4*)&qbuf[(tx + 16) * 132 + eo2 + ee];
        float4 b2 = *(const float4*)&qbuf[(tx + 32) * 132 + eo2 + ee];
        float4 b3 = *(const float4*)&qbuf[(tx + 48) * 132 + eo2 + ee];
        DOT4(s[0][0], a0, b0); DOT4(s[0][1], a0, b1); DOT4(s[0][2], a0, b2); DOT4(s[0][3], a0, b3);
        DOT4(s[1][0], a1, b0); DOT4(s[1][1], a1, b1); DOT4(s[1][2], a1, b2); DOT4(s[1][3], a1, b3);
        DOT4(s[2][0], a2, b0); DOT4(s[2][1], a2, b1); DOT4(s[2][2], a2, b2); DOT4(s[2][3], a2, b3);
        DOT4(s[3][0], a3, b0); DOT4(s[3][1], a3, b1); DOT4(s[3][2], a3, b2); DOT4(s[3][3], a3, b3);
      }
    }
  }
  cp0 += __shfl_xor(cp0, 1); cp0 += __shfl_xor(cp0, 2); cp0 += __shfl_xor(cp0, 4);
  cp1 += __shfl_xor(cp1, 1); cp1 += __shfl_xor(cp1, 2); cp1 += __shfl_xor(cp1, 4);
  if ((tid & 7) == 0) { cwl[cr] = cp0; cwl[cr + 32] = cp1; }
  __syncthreads();

#pragma unroll
  for (int i = 0; i < 4; ++i) {
    int c = ty + 16 * i;
    float cw = cwl[c];
    float f[4], mx = -1e30f;
#pragma unroll
    for (int j = 0; j < 4; ++j) {
      f[j] = s[i][j] + cw + qwl[tx + 16 * j];
      mx = fmaxf(mx, f[j]);
    }
    mx = fmaxf(mx, __shfl_xor(mx, 1));
    mx = fmaxf(mx, __shfl_xor(mx, 2));
    mx = fmaxf(mx, __shfl_xor(mx, 4));
    mx = fmaxf(mx, __shfl_xor(mx, 8));
    float sum = 0.f;
#pragma unroll
    for (int j = 0; j < 4; ++j) { f[j] = expf(f[j] - mx); sum += f[j]; }
    sum += __shfl_xor(sum, 1);
    sum += __shfl_xor(sum, 2);
    sum += __shfl_xor(sum, 4);
    sum += __shfl_xor(sum, 8);
    float inv = 1.f / sum;
    if (tx == 0) rowmax[(size_t)b * CC + c0 + c] = mx;
#pragma unroll
    for (int j = 0; j < 4; ++j) Pl[tx + 16 * j][c] = f2bf(f[j] * inv);
  }
  __syncthreads();

  for (int ep = 0; ep < EE; ep += 64) {
    if (ep) __syncthreads();
    {
      int q = tid >> 2, e16 = (tid & 3) * 16;
      const float* src = qb + (size_t)q * EE + ep + e16;
      *(float4*)&qbuf[q * 68 + e16 +  0] = *(const float4*)(src);
      *(float4*)&qbuf[q * 68 + e16 +  4] = *(const float4*)(src + 4);
      *(float4*)&qbuf[q * 68 + e16 +  8] = *(const float4*)(src + 8);
      *(float4*)&qbuf[q * 68 + e16 + 12] = *(const float4*)(src + 12);
    }
    __syncthreads();
    float s2[4][4] = {{0.f}};
#pragma unroll 8
    for (int q = 0; q < QQ; ++q) {
      float a0 = bf2f(Pl[q][ty +  0]);
      float a1 = bf2f(Pl[q][ty + 16]);
      float a2 = bf2f(Pl[q][ty + 32]);
      float a3 = bf2f(Pl[q][ty + 48]);
      float4 bv = *(const float4*)&qbuf[q * 68 + tx * 4];
      s2[0][0] += a0 * bv.x; s2[0][1] += a0 * bv.y; s2[0][2] += a0 * bv.z; s2[0][3] += a0 * bv.w;
      s2[1][0] += a1 * bv.x; s2[1][1] += a1 * bv.y; s2[1][2] += a1 * bv.z; s2[1][3] += a1 * bv.w;
      s2[2][0] += a2 * bv.x; s2[2][1] += a2 * bv.y; s2[2][2] += a2 * bv.z; s2[2][3] += a2 * bv.w;
      s2[3][0] += a3 * bv.x; s2[3][1] += a3 * bv.y; s2[3][2] += a3 * bv.z; s2[3][3] += a3 * bv.w;
    }
#pragma unroll
    for (int i = 0; i < 4; ++i) {
      int c = ty + 16 * i;
      size_t row = (size_t)(b * CC + c0 + c);
      unsigned short* arow = att + row * (size_t)FE;
      ushort4 cu = *(const ushort4*)(arow + ep + tx * 4);
      float cx = bf2f(cu.x), cy = bf2f(cu.y), cz = bf2f(cu.z), cw = bf2f(cu.w);
      ushort4 o1, o2;
      o1.x = f2bf(s2[i][0]);       o1.y = f2bf(s2[i][1]);       o1.z = f2bf(s2[i][2]);       o1.w = f2bf(s2[i][3]);
      o2.x = f2bf(cx * s2[i][0]);  o2.y = f2bf(cy * s2[i][1]);  o2.z = f2bf(cz * s2[i][2]);  o2.w = f2bf(cw * s2[i][3]);
      *(ushort4*)(arow + 1 * EE + ep + tx * 4) = o1;
      *(ushort4*)(arow + 2 * EE + ep + tx * 4) = o2;
    }
  }
}

// ---------------------------------------------------------------- q2c: softmax over c of rowmax
__global__ void k_q2c_softmax(const float* __restrict__ rowmax, float* __restrict__ q2cw) {
  int b = blockIdx.x, tid = threadIdx.x;
  __shared__ float rbuf[4], sbuf[4];
  float4 v = *(const float4*)(rowmax + (size_t)b * CC + tid * 4);
  float m = fmaxf(fmaxf(v.x, v.y), fmaxf(v.z, v.w));
  for (int off = 1; off < 64; off <<= 1) m = fmaxf(m, __shfl_xor(m, off));
  int wv = tid >> 6;
  if ((tid & 63) == 0) rbuf[wv] = m;
  __syncthreads();
  m = fmaxf(fmaxf(rbuf[0], rbuf[1]), fmaxf(rbuf[2], rbuf[3]));
  float e0 = expf(v.x - m), e1 = expf(v.y - m), e2 = expf(v.z - m), e3 = expf(v.w - m);
  float sum = e0 + e1 + e2 + e3;
  for (int off = 1; off < 64; off <<= 1) sum += __shfl_xor(sum, off);
  if ((tid & 63) == 0) sbuf[wv] = sum;
  __syncthreads();
  sum = sbuf[0] + sbuf[1] + sbuf[2] + sbuf[3];
  float inv = 1.f / sum;
  float4 o; o.x = e0 * inv; o.y = e1 * inv; o.z = e2 * inv; o.w = e3 * inv;
  *(float4*)(q2cw + (size_t)b * CC + tid * 4) = o;
}

// ---------------------------------------------------------------- q2c_att partials: sum_c w[c]*ctx_bf16[b,c,e]
__global__ void k_q2c_part(const unsigned short* __restrict__ att, const float* __restrict__ w,
                           float* __restrict__ part) {
  int b = blockIdx.y, ch = blockIdx.x;
  int e = threadIdx.x;
  const unsigned short* base = att + ((size_t)(b * CC + ch * 128)) * FE + e;
  const float* wp = w + b * CC + ch * 128;
  float acc = 0.f;
#pragma unroll 4
  for (int c = 0; c < 128; ++c) acc += wp[c] * bf2f(base[(size_t)c * FE]);
  part[(b * 8 + ch) * EE + e] = acc;
}

// ---------------------------------------------------------------- final GEMM: out = attended @ W^T + b, masked
// m97 configuration: 128x128 tile, BK=32, single-buffered LDS, 4 waves, 2-barrier loop,
// 3 blocks/CU. Fused: q2c 8-way sum (LDS prologue) + att3 = att0*q2c computed on the fly
// for K-tiles 12..15 (reg-stage + ds_write; att3 never materialized in global).
__launch_bounds__(256, 3)
__global__ void k_gemm(const unsigned short* __restrict__ A, const unsigned short* __restrict__ Bw,
                       const float* __restrict__ part, const float* __restrict__ bias,
                       const float* __restrict__ mask, float* __restrict__ out) {
  __shared__ bf16_t As[128][32];
  __shared__ bf16_t Bs[128][32];
  __shared__ float q2cl[EE];                // this batch's q2c_att (fp32)
  const int tid = threadIdx.x;
  const int lane = tid & 63;
  const int wave = tid >> 6;
  const int wr = wave >> 1, wc = wave & 1;

  // XCD-chunked swizzle: 2048 blocks, 8 XCDs -> 256 contiguous wgs per XCD.
  const int bid = blockIdx.x;
  const int wg = (bid & 7) * 256 + (bid >> 3);
  const int bcol = (wg & 7) * 128;
  const int brow = (wg >> 3) * 128;
  const int bb = brow >> 10;                // batch index (128-row tile never crosses batch)

  const int r = lane & 15, kg = lane >> 4;
  const int rk = (kg ^ (r & 3)) * 8;        // swizzled k-granule for frag reads

  // staging: one 16B granule per thread per instr; dest linear in tid.
  const int srow = tid >> 2;                // 0..63
  const int sgr = tid & 3;                  // granule 0..3
  const int ssw = (sgr ^ (srow & 3)) * 8;   // pre-swizzled source granule (elements)
  const unsigned short* gA0 = A  + (size_t)(brow + srow) * FE + ssw;
  const unsigned short* gA1 = gA0 + (size_t)64 * FE;
  const unsigned short* gB0 = Bw + (size_t)(bcol + srow) * FE + ssw;
  const unsigned short* gB1 = gB0 + (size_t)64 * FE;
  bf16_t* dA0 = &As[srow][sgr * 8];
  bf16_t* dA1 = dA0 + 64 * 32;
  bf16_t* dB0 = &Bs[srow][sgr * 8];
  bf16_t* dB1 = dB0 + 64 * 32;

  // prologue: reduce part -> q2cl (first consumer is k0=768, many barriers later)
  {
    float a = 0.f;
#pragma unroll
    for (int ch = 0; ch < 8; ++ch) a += part[(bb * 8 + ch) * EE + tid];
    q2cl[tid] = a;
  }

  f32x4 acc[4][4] = {};

  for (int k0 = 0; k0 < FE; k0 += 32) {
    if (k0 < 768) {
      gload_lds16(gA0 + k0, dA0);
      gload_lds16(gA1 + k0, dA1);
    } else {
      // fused att3: A granule = bf16( bf2f(att0) * q2c )
      const int e0 = k0 - 768;
      u16x8 va = *(const u16x8*)(gA0 + e0);
      u16x8 vb = *(const u16x8*)(gA1 + e0);
      float4 g0 = *(const float4*)&q2cl[e0 + ssw];
      float4 g1 = *(const float4*)&q2cl[e0 + ssw + 4];
      u16x8 oa, ob;
      oa[0] = f2bf(bf2f(va[0]) * g0.x); oa[1] = f2bf(bf2f(va[1]) * g0.y);
      oa[2] = f2bf(bf2f(va[2]) * g0.z); oa[3] = f2bf(bf2f(va[3]) * g0.w);
      oa[4] = f2bf(bf2f(va[4]) * g1.x); oa[5] = f2bf(bf2f(va[5]) * g1.y);
      oa[6] = f2bf(bf2f(va[6]) * g1.z); oa[7] = f2bf(bf2f(va[7]) * g1.w);
      ob[0] = f2bf(bf2f(vb[0]) * g0.x); ob[1] = f2bf(bf2f(vb[1]) * g0.y);
      ob[2] = f2bf(bf2f(vb[2]) * g0.z); ob[3] = f2bf(bf2f(vb[3]) * g0.w);
      ob[4] = f2bf(bf2f(vb[4]) * g1.x); ob[5] = f2bf(bf2f(vb[5]) * g1.y);
      ob[6] = f2bf(bf2f(vb[6]) * g1.z); ob[7] = f2bf(bf2f(vb[7]) * g1.w);
      *(u16x8*)dA0 = oa;
      *(u16x8*)dA1 = ob;
    }
    gload_lds16(gB0 + k0, dB0);
    gload_lds16(gB1 + k0, dB1);
    __syncthreads();                       // drains vmcnt+lgkmcnt: tile ready
    bf16x8 fa[4], fb[4];
#pragma unroll
    for (int m = 0; m < 4; ++m) fa[m] = *(const bf16x8*)&As[wr * 64 + m * 16 + r][rk];
#pragma unroll
    for (int n = 0; n < 4; ++n) fb[n] = *(const bf16x8*)&Bs[wc * 64 + n * 16 + r][rk];
#pragma unroll
    for (int m = 0; m < 4; ++m)
#pragma unroll
      for (int n = 0; n < 4; ++n)
        acc[m][n] = __builtin_amdgcn_mfma_f32_16x16x32_bf16(fa[m], fb[n], acc[m][n], 0, 0, 0);
    __syncthreads();                       // all reads done before next-iter overwrite
  }

#pragma unroll
  for (int m = 0; m < 4; ++m) {
#pragma unroll
    for (int n = 0; n < 4; ++n) {
#pragma unroll
      for (int reg = 0; reg < 4; ++reg) {
        int row = brow + wr * 64 + m * 16 + kg * 4 + reg;
        int col = bcol + wc * 64 + n * 16 + r;
        out[(size_t)row * FE + col] = (acc[m][n][reg] + bias[col]) * mask[row];
      }
    }
  }
}

// ---------------------------------------------------------------- launch
extern "C" void kernel_launch(void* const* d_in, const int* in_sizes, int n_in,
                              void* d_out, int out_size, void* d_ws, size_t ws_size,
                              hipStream_t stream) {
  const float* ctx  = (const float*)d_in[0];
  const float* ques = (const float*)d_in[1];
  const float* mask = (const float*)d_in[2];
  const float* w_q  = (const float*)d_in[3];
  const float* w_c  = (const float*)d_in[4];
  const float* w_m  = (const float*)d_in[5];
  const float* fW   = (const float*)d_in[6];
  const float* fb   = (const float*)d_in[7];
  float* out = (float*)d_out;

  char* ws = (char*)d_ws;
  float* qw     = (float*)(ws);                        //     8,192 B
  float* rowmax = (float*)(ws + 8192);                 //   131,072 B
  float* q2cw   = (float*)(ws + 139264);               //   131,072 B
  float* part   = (float*)(ws + 270336);               //   262,144 B
  unsigned short* attended = (unsigned short*)(ws + 1048576);   // 67,108,864 B
  unsigned short* Wb       = (unsigned short*)(ws + 68157440);  //  2,097,152 B

  k_prep<<<1536, 256, 0, stream>>>(ques, w_q, qw, fW, Wb);
  k_simpv<<<dim3(16, 32), 256, 0, stream>>>(ctx, ques, qw, w_c, w_m, rowmax, attended);
  k_q2c_softmax<<<32, 256, 0, stream>>>(rowmax, q2cw);
  k_q2c_part<<<dim3(8, 32), 256, 0, stream>>>(attended, q2cw, part);
  k_gemm<<<2048, 256, 0, stream>>>(attended, Wb, part, fb, mask, out);
}

// Round 10
// 157.791 us; speedup vs baseline: 1.0911x; 1.0699x over previous
//
#include <hip/hip_runtime.h>

// Problem constants
#define BB 32
#define CC 1024
#define QQ 64
#define EE 256
#define FE 1024
#define MM (BB*CC)   // 32768

typedef __bf16 bf16_t;
typedef bf16_t bf16x8 __attribute__((ext_vector_type(8)));
typedef float f32x4 __attribute__((ext_vector_type(4)));
typedef unsigned short u16x8 __attribute__((ext_vector_type(8)));

__device__ __forceinline__ unsigned short f2bf(float f) {
  unsigned u = __float_as_uint(f);
  u += 0x7fffu + ((u >> 16) & 1u);   // RNE
  return (unsigned short)(u >> 16);
}
__device__ __forceinline__ float bf2f(unsigned short u) {
  return __uint_as_float(((unsigned)u) << 16);
}

__device__ __forceinline__ void gload_lds16(const void* g, void* l) {
  __builtin_amdgcn_global_load_lds(
      (const __attribute__((address_space(1))) unsigned int*)g,
      (__attribute__((address_space(3))) unsigned int*)l, 16, 0, 0);
}

// ---------------------------------------------------------------- prep: qw = question.w_question; cast W to bf16
__global__ void k_prep(const float* __restrict__ question, const float* __restrict__ w_question,
                       float* __restrict__ qw,
                       const float* __restrict__ W, unsigned short* __restrict__ Wb) {
  int bx = blockIdx.x;
  if (bx < 512) {
    int gid = bx * 256 + threadIdx.x;
    int row = gid >> 6;            // (b*QQ + q), 0..2047
    int lane = gid & 63;
    const float4 q = *(const float4*)(question + (size_t)row * EE + lane * 4);
    const float4 wq = *(const float4*)(w_question + lane * 4);
    float d = q.x*wq.x + q.y*wq.y + q.z*wq.z + q.w*wq.w;
    d += __shfl_xor(d, 1);  d += __shfl_xor(d, 2);  d += __shfl_xor(d, 4);
    d += __shfl_xor(d, 8);  d += __shfl_xor(d, 16); d += __shfl_xor(d, 32);
    if (lane == 0) qw[row] = d;
  } else {
    int i = ((bx - 512) * 256 + threadIdx.x) * 4;
    float4 v = *(const float4*)(W + i);
    ushort4 o; o.x = f2bf(v.x); o.y = f2bf(v.y); o.z = f2bf(v.z); o.w = f2bf(v.w);
    *(ushort4*)(Wb + i) = o;
  }
}

#define DOT4(acc, A, Bv) acc += A.x*Bv.x + A.y*Bv.y + A.z*Bv.z + A.w*Bv.w

// ---------------------------------------------------------------- fused similarity + softmax + PV
__launch_bounds__(256)
__global__ void k_simpv(const float* __restrict__ ctx, const float* __restrict__ question,
                        const float* __restrict__ qw_g, const float* __restrict__ w_context,
                        const float* __restrict__ w_multiple,
                        float* __restrict__ rowmax, unsigned short* __restrict__ att) {
  __shared__ float qbuf[QQ * 132];          // sim: [q][128+4]; PV: [q][64+4]
  __shared__ float ck[64][36];              // ctx*w_mult chunk
  __shared__ unsigned short Pl[QQ][68];     // P[q][c] bf16
  __shared__ float cwl[64];
  __shared__ float qwl[QQ];
  const int tid = threadIdx.x;
  const int b = blockIdx.y;
  const int c0 = blockIdx.x * 64;
  const int tx = tid & 15, ty = tid >> 4;

  const float* qb = question + (size_t)b * (QQ * EE);
  if (tid < QQ) qwl[tid] = qw_g[b * QQ + tid];

  const int cr = tid >> 3, er = (tid & 7) * 4;
  const float* crow0 = ctx + ((size_t)(b * CC + c0 + cr)) * EE;
  const float* crow1 = crow0 + 32 * EE;
  unsigned short* arow0 = att + ((size_t)(b * CC + c0 + cr)) * FE;
  unsigned short* arow1 = arow0 + (size_t)32 * FE;
  float s[4][4] = {{0.f}};
  float cp0 = 0.f, cp1 = 0.f;

  for (int h = 0; h < 2; ++h) {
    if (h) __syncthreads();
    for (int idx = tid * 4; idx < QQ * 128; idx += 1024) {
      int row = idx >> 7, col = idx & 127;
      *(float4*)&qbuf[row * 132 + col] = *(const float4*)(qb + (size_t)row * EE + h * 128 + col);
    }
    for (int eo2 = 0; eo2 < 128; eo2 += 32) {
      const int eo = h * 128 + eo2;
      float4 cv0 = *(const float4*)(crow0 + eo + er);
      float4 cv1 = *(const float4*)(crow1 + eo + er);
      float4 wc = *(const float4*)(w_context + eo + er);
      float4 wm = *(const float4*)(w_multiple + eo + er);
      cp0 += cv0.x*wc.x + cv0.y*wc.y + cv0.z*wc.z + cv0.w*wc.w;
      cp1 += cv1.x*wc.x + cv1.y*wc.y + cv1.z*wc.z + cv1.w*wc.w;
      ushort4 u0, u1;
      u0.x = f2bf(cv0.x); u0.y = f2bf(cv0.y); u0.z = f2bf(cv0.z); u0.w = f2bf(cv0.w);
      u1.x = f2bf(cv1.x); u1.y = f2bf(cv1.y); u1.z = f2bf(cv1.z); u1.w = f2bf(cv1.w);
      *(ushort4*)(arow0 + eo + er) = u0;
      *(ushort4*)(arow1 + eo + er) = u1;
      __syncthreads();
      float4 m0, m1;
      m0.x = cv0.x*wm.x; m0.y = cv0.y*wm.y; m0.z = cv0.z*wm.z; m0.w = cv0.w*wm.w;
      m1.x = cv1.x*wm.x; m1.y = cv1.y*wm.y; m1.z = cv1.z*wm.z; m1.w = cv1.w*wm.w;
      *(float4*)&ck[cr][er] = m0;
      *(float4*)&ck[cr + 32][er] = m1;
      __syncthreads();
#pragma unroll
      for (int ee = 0; ee < 32; ee += 4) {
        float4 a0 = *(const float4*)&ck[ty +  0][ee];
        float4 a1 = *(const float4*)&ck[ty + 16][ee];
        float4 a2 = *(const float4*)&ck[ty + 32][ee];
        float4 a3 = *(const float4*)&ck[ty + 48][ee];
        float4 b0 = *(const float4*)&qbuf[(tx +  0) * 132 + eo2 + ee];
        float4 b1 = *(const float4*)&qbuf[(tx + 16) * 132 + eo2 + ee];
        float4 b2 = *(const float4*)&qbuf[(tx + 32) * 132 + eo2 + ee];
        float4 b3 = *(const float4*)&qbuf[(tx + 48) * 132 + eo2 + ee];
        DOT4(s[0][0], a0, b0); DOT4(s[0][1], a0, b1); DOT4(s[0][2], a0, b2); DOT4(s[0][3], a0, b3);
        DOT4(s[1][0], a1, b0); DOT4(s[1][1], a1, b1); DOT4(s[1][2], a1, b2); DOT4(s[1][3], a1, b3);
        DOT4(s[2][0], a2, b0); DOT4(s[2][1], a2, b1); DOT4(s[2][2], a2, b2); DOT4(s[2][3], a2, b3);
        DOT4(s[3][0], a3, b0); DOT4(s[3][1], a3, b1); DOT4(s[3][2], a3, b2); DOT4(s[3][3], a3, b3);
      }
    }
  }
  cp0 += __shfl_xor(cp0, 1); cp0 += __shfl_xor(cp0, 2); cp0 += __shfl_xor(cp0, 4);
  cp1 += __shfl_xor(cp1, 1); cp1 += __shfl_xor(cp1, 2); cp1 += __shfl_xor(cp1, 4);
  if ((tid & 7) == 0) { cwl[cr] = cp0; cwl[cr + 32] = cp1; }
  __syncthreads();

#pragma unroll
  for (int i = 0; i < 4; ++i) {
    int c = ty + 16 * i;
    float cw = cwl[c];
    float f[4], mx = -1e30f;
#pragma unroll
    for (int j = 0; j < 4; ++j) {
      f[j] = s[i][j] + cw + qwl[tx + 16 * j];
      mx = fmaxf(mx, f[j]);
    }
    mx = fmaxf(mx, __shfl_xor(mx, 1));
    mx = fmaxf(mx, __shfl_xor(mx, 2));
    mx = fmaxf(mx, __shfl_xor(mx, 4));
    mx = fmaxf(mx, __shfl_xor(mx, 8));
    float sum = 0.f;
#pragma unroll
    for (int j = 0; j < 4; ++j) { f[j] = expf(f[j] - mx); sum += f[j]; }
    sum += __shfl_xor(sum, 1);
    sum += __shfl_xor(sum, 2);
    sum += __shfl_xor(sum, 4);
    sum += __shfl_xor(sum, 8);
    float inv = 1.f / sum;
    if (tx == 0) rowmax[(size_t)b * CC + c0 + c] = mx;
#pragma unroll
    for (int j = 0; j < 4; ++j) Pl[tx + 16 * j][c] = f2bf(f[j] * inv);
  }
  __syncthreads();

  for (int ep = 0; ep < EE; ep += 64) {
    if (ep) __syncthreads();
    {
      int q = tid >> 2, e16 = (tid & 3) * 16;
      const float* src = qb + (size_t)q * EE + ep + e16;
      *(float4*)&qbuf[q * 68 + e16 +  0] = *(const float4*)(src);
      *(float4*)&qbuf[q * 68 + e16 +  4] = *(const float4*)(src + 4);
      *(float4*)&qbuf[q * 68 + e16 +  8] = *(const float4*)(src + 8);
      *(float4*)&qbuf[q * 68 + e16 + 12] = *(const float4*)(src + 12);
    }
    __syncthreads();
    float s2[4][4] = {{0.f}};
#pragma unroll 8
    for (int q = 0; q < QQ; ++q) {
      float a0 = bf2f(Pl[q][ty +  0]);
      float a1 = bf2f(Pl[q][ty + 16]);
      float a2 = bf2f(Pl[q][ty + 32]);
      float a3 = bf2f(Pl[q][ty + 48]);
      float4 bv = *(const float4*)&qbuf[q * 68 + tx * 4];
      s2[0][0] += a0 * bv.x; s2[0][1] += a0 * bv.y; s2[0][2] += a0 * bv.z; s2[0][3] += a0 * bv.w;
      s2[1][0] += a1 * bv.x; s2[1][1] += a1 * bv.y; s2[1][2] += a1 * bv.z; s2[1][3] += a1 * bv.w;
      s2[2][0] += a2 * bv.x; s2[2][1] += a2 * bv.y; s2[2][2] += a2 * bv.z; s2[2][3] += a2 * bv.w;
      s2[3][0] += a3 * bv.x; s2[3][1] += a3 * bv.y; s2[3][2] += a3 * bv.z; s2[3][3] += a3 * bv.w;
    }
#pragma unroll
    for (int i = 0; i < 4; ++i) {
      int c = ty + 16 * i;
      size_t row = (size_t)(b * CC + c0 + c);
      unsigned short* arow = att + row * (size_t)FE;
      ushort4 cu = *(const ushort4*)(arow + ep + tx * 4);
      float cx = bf2f(cu.x), cy = bf2f(cu.y), cz = bf2f(cu.z), cw = bf2f(cu.w);
      ushort4 o1, o2;
      o1.x = f2bf(s2[i][0]);       o1.y = f2bf(s2[i][1]);       o1.z = f2bf(s2[i][2]);       o1.w = f2bf(s2[i][3]);
      o2.x = f2bf(cx * s2[i][0]);  o2.y = f2bf(cy * s2[i][1]);  o2.z = f2bf(cz * s2[i][2]);  o2.w = f2bf(cw * s2[i][3]);
      *(ushort4*)(arow + 1 * EE + ep + tx * 4) = o1;
      *(ushort4*)(arow + 2 * EE + ep + tx * 4) = o2;
    }
  }
}

// ---------------------------------------------------------------- q2c: softmax over c of rowmax
__global__ void k_q2c_softmax(const float* __restrict__ rowmax, float* __restrict__ q2cw) {
  int b = blockIdx.x, tid = threadIdx.x;
  __shared__ float rbuf[4], sbuf[4];
  float4 v = *(const float4*)(rowmax + (size_t)b * CC + tid * 4);
  float m = fmaxf(fmaxf(v.x, v.y), fmaxf(v.z, v.w));
  for (int off = 1; off < 64; off <<= 1) m = fmaxf(m, __shfl_xor(m, off));
  int wv = tid >> 6;
  if ((tid & 63) == 0) rbuf[wv] = m;
  __syncthreads();
  m = fmaxf(fmaxf(rbuf[0], rbuf[1]), fmaxf(rbuf[2], rbuf[3]));
  float e0 = expf(v.x - m), e1 = expf(v.y - m), e2 = expf(v.z - m), e3 = expf(v.w - m);
  float sum = e0 + e1 + e2 + e3;
  for (int off = 1; off < 64; off <<= 1) sum += __shfl_xor(sum, off);
  if ((tid & 63) == 0) sbuf[wv] = sum;
  __syncthreads();
  sum = sbuf[0] + sbuf[1] + sbuf[2] + sbuf[3];
  float inv = 1.f / sum;
  float4 o; o.x = e0 * inv; o.y = e1 * inv; o.z = e2 * inv; o.w = e3 * inv;
  *(float4*)(q2cw + (size_t)b * CC + tid * 4) = o;
}

// ---------------------------------------------------------------- q2c_att partials: sum_c w[c]*ctx_bf16[b,c,e]
__global__ void k_q2c_part(const unsigned short* __restrict__ att, const float* __restrict__ w,
                           float* __restrict__ part) {
  int b = blockIdx.y, ch = blockIdx.x;
  int e = threadIdx.x;
  const unsigned short* base = att + ((size_t)(b * CC + ch * 128)) * FE + e;
  const float* wp = w + b * CC + ch * 128;
  float acc = 0.f;
#pragma unroll 4
  for (int c = 0; c < 128; ++c) acc += wp[c] * bf2f(base[(size_t)c * FE]);
  part[(b * 8 + ch) * EE + e] = acc;
}

// ---------------------------------------------------------------- final GEMM: out = attended @ W^T + b, masked
// 256x128 block, BK=64, 4 waves (2Mx2N), wave tile 128x64 (8x4 rep of 16x16x32, ks-serial),
// single-buffered 48KB LDS, 2-barrier loop, 2 blocks/CU. 3-bit XOR swizzle (128B rows,
// proven conflict-free R4-R6). Fused q2c-sum prologue + on-the-fly att3 for k0>=768.
__launch_bounds__(256, 2)
__global__ void k_gemm(const unsigned short* __restrict__ A, const unsigned short* __restrict__ Bw,
                       const float* __restrict__ part, const float* __restrict__ bias,
                       const float* __restrict__ mask, float* __restrict__ out) {
  __shared__ bf16_t As[256][64];            // 32KB
  __shared__ bf16_t Bs[128][64];            // 16KB
  __shared__ float q2cl[EE];                // 1KB
  const int tid = threadIdx.x;
  const int lane = tid & 63;
  const int wave = tid >> 6;
  const int wr = wave >> 1, wc = wave & 1;

  // XCD-chunked swizzle: 1024 blocks, 8 XCDs -> 128 contiguous wgs per XCD
  // (16 row-panels x 8 col-tiles, col fastest).
  const int bid = blockIdx.x;
  const int wg = (bid & 7) * 128 + (bid >> 3);
  const int bcol = (wg & 7) * 128;
  const int brow = (wg >> 3) * 256;
  const int bb = brow >> 10;                // batch (256-row tile never crosses batch)

  const int r = lane & 15, kg = lane >> 4;
  const int rx = r & 7;                     // read-side XOR key

  // staging: granule gi = i*256 + tid; row = gi>>3, slot = gi&7; dest linear.
  const int srow = tid >> 3;                // 0..31 base row (instr i adds i*32)
  const int ssw = ((tid & 7) ^ (srow & 7)) * 8;   // pre-swizzled source slot (elements)
  const unsigned short* gA = A  + (size_t)(brow + srow) * FE + ssw;
  const unsigned short* gB = Bw + (size_t)(bcol + srow) * FE + ssw;
  bf16_t* dA = (bf16_t*)As + tid * 8;
  bf16_t* dB = (bf16_t*)Bs + tid * 8;

  // prologue: reduce part -> q2cl (first consumed at k0=768)
  {
    float a = 0.f;
#pragma unroll
    for (int ch = 0; ch < 8; ++ch) a += part[(bb * 8 + ch) * EE + tid];
    q2cl[tid] = a;
  }

  f32x4 acc[8][4] = {};

  for (int k0 = 0; k0 < FE; k0 += 64) {
    if (k0 < 768) {
#pragma unroll
      for (int i = 0; i < 8; ++i)
        gload_lds16(gA + (size_t)(i * 32) * FE + k0, dA + i * 2048);
    } else {
      // fused att3: A = bf16( bf2f(att0) * q2c ), reg-staged + ds_write
      const int e0 = k0 - 768;
      float4 g0 = *(const float4*)&q2cl[e0 + ssw];
      float4 g1 = *(const float4*)&q2cl[e0 + ssw + 4];
#pragma unroll
      for (int i = 0; i < 8; ++i) {
        u16x8 v = *(const u16x8*)(gA + (size_t)(i * 32) * FE + e0);
        u16x8 o;
        o[0] = f2bf(bf2f(v[0]) * g0.x); o[1] = f2bf(bf2f(v[1]) * g0.y);
        o[2] = f2bf(bf2f(v[2]) * g0.z); o[3] = f2bf(bf2f(v[3]) * g0.w);
        o[4] = f2bf(bf2f(v[4]) * g1.x); o[5] = f2bf(bf2f(v[5]) * g1.y);
        o[6] = f2bf(bf2f(v[6]) * g1.z); o[7] = f2bf(bf2f(v[7]) * g1.w);
        *(u16x8*)(dA + i * 2048) = o;
      }
    }
#pragma unroll
    for (int i = 0; i < 4; ++i)
      gload_lds16(gB + (size_t)(i * 32) * FE + k0, dB + i * 2048);
    __syncthreads();                       // drains vmcnt+lgkmcnt: tile ready

#pragma unroll
    for (int ks = 0; ks < 2; ++ks) {
      bf16x8 fa[8], fb[4];
#pragma unroll
      for (int m = 0; m < 8; ++m)
        fa[m] = *(const bf16x8*)&As[wr * 128 + m * 16 + r][((ks * 4 + kg) ^ rx) * 8];
#pragma unroll
      for (int n = 0; n < 4; ++n)
        fb[n] = *(const bf16x8*)&Bs[wc * 64 + n * 16 + r][((ks * 4 + kg) ^ rx) * 8];
#pragma unroll
      for (int m = 0; m < 8; ++m)
#pragma unroll
        for (int n = 0; n < 4; ++n)
          acc[m][n] = __builtin_amdgcn_mfma_f32_16x16x32_bf16(fa[m], fb[n], acc[m][n], 0, 0, 0);
    }
    __syncthreads();                       // all reads done before next-iter overwrite
  }

#pragma unroll
  for (int m = 0; m < 8; ++m) {
#pragma unroll
    for (int n = 0; n < 4; ++n) {
#pragma unroll
      for (int reg = 0; reg < 4; ++reg) {
        int row = brow + wr * 128 + m * 16 + kg * 4 + reg;
        int col = bcol + wc * 64 + n * 16 + r;
        out[(size_t)row * FE + col] = (acc[m][n][reg] + bias[col]) * mask[row];
      }
    }
  }
}

// ---------------------------------------------------------------- launch
extern "C" void kernel_launch(void* const* d_in, const int* in_sizes, int n_in,
                              void* d_out, int out_size, void* d_ws, size_t ws_size,
                              hipStream_t stream) {
  const float* ctx  = (const float*)d_in[0];
  const float* ques = (const float*)d_in[1];
  const float* mask = (const float*)d_in[2];
  const float* w_q  = (const float*)d_in[3];
  const float* w_c  = (const float*)d_in[4];
  const float* w_m  = (const float*)d_in[5];
  const float* fW   = (const float*)d_in[6];
  const float* fb   = (const float*)d_in[7];
  float* out = (float*)d_out;

  char* ws = (char*)d_ws;
  float* qw     = (float*)(ws);                        //     8,192 B
  float* rowmax = (float*)(ws + 8192);                 //   131,072 B
  float* q2cw   = (float*)(ws + 139264);               //   131,072 B
  float* part   = (float*)(ws + 270336);               //   262,144 B
  unsigned short* attended = (unsigned short*)(ws + 1048576);   // 67,108,864 B
  unsigned short* Wb       = (unsigned short*)(ws + 68157440);  //  2,097,152 B

  k_prep<<<1536, 256, 0, stream>>>(ques, w_q, qw, fW, Wb);
  k_simpv<<<dim3(16, 32), 256, 0, stream>>>(ctx, ques, qw, w_c, w_m, rowmax, attended);
  k_q2c_softmax<<<32, 256, 0, stream>>>(rowmax, q2cw);
  k_q2c_part<<<dim3(8, 32), 256, 0, stream>>>(attended, q2cw, part);
  k_gemm<<<1024, 256, 0, stream>>>(attended, Wb, part, fb, mask, out);
}